// Round 2
// baseline (40.764 us; speedup 1.0000x reference)
//
#include <hip/hip_runtime.h>
#include <hip/hip_bf16.h>

// Decompose: algebraically a single 5x5 conv with scalar taps
//   a_k = wS_k . wE_k  (k = i*5+j), bias = sum_k (wS_k . bE_k + bS_k)
//   out = clip( (sum_k a_k * xp[h+i, w+j] + bias) / 25, 0, 1 )
// over xp = reflect-pad(clip(x,0,1), 2). Shapes: x (4,3,1024,1024) fp32.

#define HH 1024
#define WW 1024
#define NIMG 12
#define TBH 8              // output rows per block
#define ROWS (TBH + 4)     // 12 staged padded rows
#define PITCH 1028         // LDS floats per row: padded cols 0..1027

typedef float f32x4 __attribute__((ext_vector_type(4)));

__global__ void prep_kernel(const float* __restrict__ wE,
                            const float* __restrict__ bE,
                            const float* __restrict__ wS,
                            const float* __restrict__ bS,
                            float* __restrict__ ws) {
    __shared__ float csh[25];
    int k = threadIdx.x;
    if (k < 25) {
        float a = 0.f, c = 0.f;
        #pragma unroll 8
        for (int d = 0; d < 64; ++d) {
            float s = wS[k * 64 + d];
            a = fmaf(s, wE[k * 64 + d], a);
            c = fmaf(s, bE[k * 64 + d], c);
        }
        ws[k] = a * (1.f / 25.f);
        csh[k] = c + bS[k];
    }
    __syncthreads();
    if (k == 0) {
        float b = 0.f;
        for (int i = 0; i < 25; ++i) b += csh[i];
        ws[25] = b * (1.f / 25.f);
    }
}

__device__ __forceinline__ float clip01(float v) {
    return fminf(fmaxf(v, 0.f), 1.f);
}

__global__ __launch_bounds__(256) void conv5_kernel(const float* __restrict__ x,
                                                    const float* __restrict__ wsbuf,
                                                    float* __restrict__ out) {
    // XCD-aware bijective swizzle: gridDim.x = 1536, 1536 % 8 == 0.
    int nwg = gridDim.x;
    int cpx = nwg >> 3;                       // blocks per XCD chunk
    int l = (blockIdx.x & 7) * cpx + (blockIdx.x >> 3);
    int img = l >> 7;                         // 128 row-blocks per image
    int rb = l & 127;
    int row0 = rb * TBH;

    const float* src = x + (size_t)img * (HH * WW);
    int tid = threadIdx.x;

    __shared__ float tile[ROWS][PITCH];

    // Uniform weight loads -> SGPRs.
    float wv[25];
    #pragma unroll
    for (int k = 0; k < 25; ++k) wv[k] = wsbuf[k];
    float bias = wsbuf[25];

    // ---- Stage 12 padded rows into LDS (reflect pad, clip to [0,1]) ----
    #pragma unroll
    for (int ir = 0; ir < ROWS; ++ir) {
        int prow = row0 - 2 + ir;
        int sr = prow < 0 ? -prow : (prow >= HH ? 2 * HH - 2 - prow : prow);
        const float* rp = src + (size_t)sr * WW;

        int p = 4 * tid;                       // padded col base this thread stages
        float4 v;
        if (tid == 0) {
            // p = 0..3 -> source cols -2..1 -> reflect: 2,1,0,1
            v.x = rp[2]; v.y = rp[1]; v.z = rp[0]; v.w = rp[1];
        } else {
            int q = p - 2;                     // q >= 2, even -> 8B aligned
            const float2* rp2 = (const float2*)(rp + q);
            float2 a0 = rp2[0];
            float2 a1 = rp2[1];
            v.x = a0.x; v.y = a0.y; v.z = a1.x; v.w = a1.y;
        }
        v.x = clip01(v.x); v.y = clip01(v.y); v.z = clip01(v.z); v.w = clip01(v.w);
        *(float4*)&tile[ir][p] = v;

        if (tid == 1) {
            // tail p = 1024..1027 -> source cols 1022..1025 -> 1022,1023,1022,1021
            float4 e;
            e.x = clip01(rp[1022]); e.y = clip01(rp[1023]);
            e.z = clip01(rp[1022]); e.w = clip01(rp[1021]);
            *(float4*)&tile[ir][1024] = e;
        }
    }
    __syncthreads();

    // ---- Sliding-window compute: each LDS row read once ----
    float acc[TBH][4];
    #pragma unroll
    for (int r = 0; r < TBH; ++r)
        #pragma unroll
        for (int c = 0; c < 4; ++c) acc[r][c] = 0.f;

    int cbase = 4 * tid;  // output col base == padded col base for reads
    #pragma unroll
    for (int ir = 0; ir < ROWS; ++ir) {
        float4 u = *(const float4*)&tile[ir][cbase];
        float4 w4 = *(const float4*)&tile[ir][cbase + 4];
        float r8[8] = {u.x, u.y, u.z, u.w, w4.x, w4.y, w4.z, w4.w};
        #pragma unroll
        for (int dr = 0; dr < 5; ++dr) {
            int orow = ir - dr;
            if (orow < 0 || orow >= TBH) continue;
            #pragma unroll
            for (int j = 0; j < 5; ++j) {
                float wj = wv[dr * 5 + j];
                #pragma unroll
                for (int c = 0; c < 4; ++c)
                    acc[orow][c] = fmaf(wj, r8[c + j], acc[orow][c]);
            }
        }
    }

    // ---- Epilogue: bias, clip, nontemporal coalesced 16B stores ----
    float* op = out + (size_t)img * (HH * WW) + (size_t)row0 * WW + cbase;
    #pragma unroll
    for (int orow = 0; orow < TBH; ++orow) {
        f32x4 o;
        o.x = clip01(acc[orow][0] + bias);
        o.y = clip01(acc[orow][1] + bias);
        o.z = clip01(acc[orow][2] + bias);
        o.w = clip01(acc[orow][3] + bias);
        __builtin_nontemporal_store(o, (f32x4*)(op + (size_t)orow * WW));
    }
}

extern "C" void kernel_launch(void* const* d_in, const int* in_sizes, int n_in,
                              void* d_out, int out_size, void* d_ws, size_t ws_size,
                              hipStream_t stream) {
    const float* x  = (const float*)d_in[0];
    const float* wE = (const float*)d_in[1];
    const float* bE = (const float*)d_in[2];
    const float* wS = (const float*)d_in[3];
    const float* bS = (const float*)d_in[4];
    float* out = (float*)d_out;
    float* ws  = (float*)d_ws;

    prep_kernel<<<1, 64, 0, stream>>>(wE, bE, wS, bS, ws);

    int nblocks = NIMG * (HH / TBH);   // 12 * 128 = 1536
    conv5_kernel<<<nblocks, 256, 0, stream>>>(x, ws, out);
}

// Round 3
// 30.379 us; speedup vs baseline: 1.3418x; 1.3418x over previous
//
#include <hip/hip_runtime.h>
#include <hip/hip_bf16.h>

// Decompose: algebraically a single 5x5 conv with scalar taps
//   a_k = wS_k . wE_k  (k = i*5+j), bias = sum_k (wS_k . bE_k + bS_k)
//   out = clip( (sum_k a_k * xp[h+i, w+j] + bias) / 25, 0, 1 )
// over xp = reflect-pad(clip(x,0,1), 2). Shapes: x (4,3,1024,1024) fp32.
//
// R2 redesign: no LDS, no barrier. Each thread owns a 4-col x 8-row strip,
// loads 12 input rows as two 8B-aligned dwordx4 each (all independent ->
// deep MLP), rotates accumulators in registers. Latency hidden by ~50-60%
// occupancy instead of 28% LDS-limited.

#define HH 1024
#define WW 1024
#define NIMG 12
#define TBH 8              // output rows per thread/block-row
#define ROWS (TBH + 4)     // 12 input rows touched

typedef float f32x4 __attribute__((ext_vector_type(4)));

__device__ __forceinline__ float clip01(float v) {
    return fminf(fmaxf(v, 0.f), 1.f);
}

// ws[0..24] = (wS_k.wE_k)/25 ; ws[25] = (sum_k wS_k.bE_k + bS_k)/25
__global__ __launch_bounds__(256) void prep_kernel(const float* __restrict__ wE,
                                                   const float* __restrict__ bE,
                                                   const float* __restrict__ wS,
                                                   const float* __restrict__ bS,
                                                   float* __restrict__ ws) {
    __shared__ float pa[25][8];
    __shared__ float pc[25][8];
    int t = threadIdx.x;
    if (t < 200) {
        int k = t >> 3, seg = t & 7;
        int base = k * 64 + seg * 8;
        f32x4 s0 = *(const f32x4*)(wS + base);
        f32x4 s1 = *(const f32x4*)(wS + base + 4);
        f32x4 e0 = *(const f32x4*)(wE + base);
        f32x4 e1 = *(const f32x4*)(wE + base + 4);
        f32x4 b0 = *(const f32x4*)(bE + base);
        f32x4 b1 = *(const f32x4*)(bE + base + 4);
        float a = s0.x*e0.x + s0.y*e0.y + s0.z*e0.z + s0.w*e0.w
                + s1.x*e1.x + s1.y*e1.y + s1.z*e1.z + s1.w*e1.w;
        float c = s0.x*b0.x + s0.y*b0.y + s0.z*b0.z + s0.w*b0.w
                + s1.x*b1.x + s1.y*b1.y + s1.z*b1.z + s1.w*b1.w;
        pa[k][seg] = a;
        pc[k][seg] = c;
    }
    __syncthreads();
    if (t < 25) {
        float a = 0.f, c = 0.f;
        #pragma unroll
        for (int i = 0; i < 8; ++i) { a += pa[t][i]; c += pc[t][i]; }
        ws[t] = a * (1.f / 25.f);
        pc[t][0] = c + bS[t];
    }
    __syncthreads();
    if (t == 0) {
        float b = 0.f;
        #pragma unroll
        for (int i = 0; i < 25; ++i) b += pc[i][0];
        ws[25] = b * (1.f / 25.f);
    }
}

__global__ __launch_bounds__(256) void conv5_kernel(const float* __restrict__ x,
                                                    const float* __restrict__ wsbuf,
                                                    float* __restrict__ out) {
    // XCD-aware bijective swizzle: gridDim.x = 1536, 1536 % 8 == 0.
    int nwg = gridDim.x;
    int cpx = nwg >> 3;
    int l = (blockIdx.x & 7) * cpx + (blockIdx.x >> 3);
    int img = l >> 7;                         // 128 row-blocks per image
    int rb = l & 127;
    int row0 = rb * TBH;

    const float* src = x + (size_t)img * (HH * WW);
    int tid = threadIdx.x;
    int cbase = tid * 4;                      // output col base

    // Uniform scalar loads -> SGPRs.
    float wv[25];
    #pragma unroll
    for (int k = 0; k < 25; ++k) wv[k] = wsbuf[k];
    float bias = wsbuf[25];

    // Column window: need source cols cbase-2 .. cbase+5 (reflect at edges).
    // Interior: A = [c-2..c+1], B = [c+2..c+5]   (both 8B-aligned dwordx4)
    // lt (c==0):    A=[0..3], B=[2..5]  -> window {A2,A1,A0,A1,B0,B1,B2,B3}
    // rt (c==1020): A=[1018..1021], B=[1020..1023] -> {A0,A1,A2,A3,B2,B3,B2,B1}
    bool lt = (cbase == 0);
    bool rt = (cbase == 1020);
    int qa = lt ? 0 : cbase - 2;
    int qb = rt ? 1020 : cbase + 2;

    float acc[TBH][4];
    #pragma unroll
    for (int r = 0; r < TBH; ++r)
        #pragma unroll
        for (int c = 0; c < 4; ++c) acc[r][c] = 0.f;

    #pragma unroll
    for (int ir = 0; ir < ROWS; ++ir) {
        int prow = row0 - 2 + ir;
        int sr = prow < 0 ? -prow : (prow >= HH ? 2 * HH - 2 - prow : prow);
        const float* rp = src + (size_t)sr * WW;
        f32x4 A = *(const f32x4*)(rp + qa);
        f32x4 B = *(const f32x4*)(rp + qb);

        float r8[8];
        if (lt) {
            r8[0]=A.z; r8[1]=A.y; r8[2]=A.x; r8[3]=A.y;
            r8[4]=B.x; r8[5]=B.y; r8[6]=B.z; r8[7]=B.w;
        } else if (rt) {
            r8[0]=A.x; r8[1]=A.y; r8[2]=A.z; r8[3]=A.w;
            r8[4]=B.z; r8[5]=B.w; r8[6]=B.z; r8[7]=B.y;
        } else {
            r8[0]=A.x; r8[1]=A.y; r8[2]=A.z; r8[3]=A.w;
            r8[4]=B.x; r8[5]=B.y; r8[6]=B.z; r8[7]=B.w;
        }
        #pragma unroll
        for (int j = 0; j < 8; ++j) r8[j] = clip01(r8[j]);

        #pragma unroll
        for (int dr = 0; dr < 5; ++dr) {
            int orow = ir - dr;
            if (orow < 0 || orow >= TBH) continue;
            #pragma unroll
            for (int j = 0; j < 5; ++j) {
                float wj = wv[dr * 5 + j];
                #pragma unroll
                for (int c = 0; c < 4; ++c)
                    acc[orow][c] = fmaf(wj, r8[c + j], acc[orow][c]);
            }
        }
    }

    // Epilogue: bias, clip, nontemporal coalesced 16B stores.
    float* op = out + (size_t)img * (HH * WW) + (size_t)row0 * WW + cbase;
    #pragma unroll
    for (int orow = 0; orow < TBH; ++orow) {
        f32x4 o;
        o.x = clip01(acc[orow][0] + bias);
        o.y = clip01(acc[orow][1] + bias);
        o.z = clip01(acc[orow][2] + bias);
        o.w = clip01(acc[orow][3] + bias);
        __builtin_nontemporal_store(o, (f32x4*)(op + (size_t)orow * WW));
    }
}

extern "C" void kernel_launch(void* const* d_in, const int* in_sizes, int n_in,
                              void* d_out, int out_size, void* d_ws, size_t ws_size,
                              hipStream_t stream) {
    const float* x  = (const float*)d_in[0];
    const float* wE = (const float*)d_in[1];
    const float* bE = (const float*)d_in[2];
    const float* wS = (const float*)d_in[3];
    const float* bS = (const float*)d_in[4];
    float* out = (float*)d_out;
    float* ws  = (float*)d_ws;

    prep_kernel<<<1, 256, 0, stream>>>(wE, bE, wS, bS, ws);

    int nblocks = NIMG * (HH / TBH);   // 12 * 128 = 1536
    conv5_kernel<<<nblocks, 256, 0, stream>>>(x, ws, out);
}